// Round 12
// baseline (270.420 us; speedup 1.0000x reference)
//
#include <hip/hip_runtime.h>
#include <hip/hip_bf16.h>

// Problem constants
#define N_TOK 8192
#define INL   512
#define OUTL  512
#define NE    8
#define NI    16
#define EOFF  (OUTL * INL)   // elems per expert in wt

typedef unsigned short ushort_t;
typedef unsigned int   uint_t;
typedef short  short8  __attribute__((ext_vector_type(8)));
typedef float  floatx4 __attribute__((ext_vector_type(4)));

// ---------------- workspace layout (bytes) ----------------
#define WS_GAM    2048u      // float[8]   : gam[e]
#define WS_RGAM   2080u      // float[8]   : router_gamma[e]
#define WS_BET    2112u      // float[4096]: bet_eff[e][d] = bet + gam*b
#define WS_SELE   18496u     // int[8192]  : e0 | e1<<8
#define WS_SELW   51264u     // float4[8192]: {rw0*gam0, rw1*gam1, rw0, rw1}
#define WS_WT     182336u    // ushort[8*512*512] : W^T bf16 [e][d][l]

__device__ __forceinline__ uint_t pkbf(float a, float b) {
    __hip_bfloat162 h = __float22bfloat162_rn(make_float2(a, b));  // v_cvt_pk_bf16_f32
    union { __hip_bfloat162 h2; uint_t u; } cv;
    cv.h2 = h;
    return cv.u;
}
// async global->LDS DMA, 16 B per lane; LDS dest = wave-uniform base + lane*16
__device__ __forceinline__ void dma16(const ushort_t* g, ushort_t* l) {
    __builtin_amdgcn_global_load_lds(
        (const __attribute__((address_space(1))) void*)g,
        (__attribute__((address_space(3))) void*)l,
        16, 0, 0);
}

// ================= K1: bet_eff + stats =================
// blocks [0,128): bet_eff  (e = bx>>4; dBase = (bx&15)*32)
// block  128:     stats -> wsGam, wsRgam
__global__ __launch_bounds__(256)
void k_betstats(const float* __restrict__ ins,
                const float* __restrict__ gamma_w,
                const float* __restrict__ rmod_w,
                const float* __restrict__ beta_w,
                const float* __restrict__ expert_b,
                float* __restrict__ wsBet,
                float* __restrict__ wsGam, float* __restrict__ wsRgam) {
    __shared__ float sS[INL];
    __shared__ float red[256];
    __shared__ float aux[1];
    int bx = blockIdx.x, tid = threadIdx.x;

    for (int h = tid; h < INL; h += 256) {
        float a = 0.f;
        for (int n = 0; n < NI; ++n) a += ins[n * INL + h];
        sS[h] = a;
    }
    __syncthreads();

    if (bx < 128) {
        int e = bx >> 4, dBase = (bx & 15) * 32;
        if (tid < 64) {
            float g = 0.f;
            for (int j = 0; j < 8; ++j) g += sS[tid * 8 + j] * gamma_w[e * INL + tid * 8 + j];
            for (int off = 32; off >= 1; off >>= 1) g += __shfl_xor(g, off, 64);
            if (tid == 0) aux[0] = g * (1.f / NI);
        }
        int doff = tid & 31, hq = tid >> 5;
        float a = 0.f;
        for (int j = 0; j < 64; ++j) {
            int h = hq * 64 + j;
            a += sS[h] * beta_w[(e * INL + h) * OUTL + dBase + doff];
        }
        red[tid] = a;
        __syncthreads();
        if (tid < 32) {
            float t = 0.f;
            for (int k = 0; k < 8; ++k) t += red[k * 32 + tid];
            int d = dBase + tid;
            wsBet[e * OUTL + d] = t * (1.f / NI) + aux[0] * expert_b[e * OUTL + d];
        }
        return;
    }

    // stats block
    if (tid < 64) {
        int e = tid & 7, qq = tid >> 3;
        float g = 0.f, r = 0.f;
        for (int j = 0; j < 64; ++j) {
            int h = qq * 64 + j;
            float sv = sS[h];
            g += sv * gamma_w[e * INL + h];
            r += sv * rmod_w[h * NE + e];
        }
        red[tid] = g; red[64 + tid] = r;
    }
    __syncthreads();
    if (tid < NE) {
        float g = 0.f, r = 0.f;
        for (int qq = 0; qq < 8; ++qq) { g += red[qq * 8 + tid]; r += red[64 + qq * 8 + tid]; }
        wsGam[tid]  = g * (1.f / NI);
        wsRgam[tid] = r * (1.f / NI);
    }
}

// ================= K2: router (fp32 logits), 16 tokens/block =================
__global__ void k_route(const float* __restrict__ x,
                        const float* __restrict__ gate_w,
                        const float* __restrict__ wsGam,
                        const float* __restrict__ wsRgam,
                        int* __restrict__ selE, float4* __restrict__ selW) {
    __shared__ float gateT[NE * INL];   // 16 KB, [e][l]
    int tid = threadIdx.x;
    for (int i = 0; i < 16; ++i) {
        int f = tid + 256 * i;
        float v = gate_w[f];
        gateT[(f & 7) * INL + (f >> 3)] = v;
    }
    __syncthreads();

    int w = tid >> 6, lane = tid & 63;
    int tbase = blockIdx.x * 16 + w * 4;

    for (int tt = 0; tt < 4; ++tt) {
        int t = tbase + tt;
        float2 xv[4];
        for (int i = 0; i < 4; ++i)
            xv[i] = *(const float2*)(x + (size_t)t * INL + 2 * lane + 128 * i);

        float acc[NE];
        for (int e = 0; e < NE; ++e) acc[e] = 0.f;
        for (int i = 0; i < 4; ++i) {
            int c = 2 * lane + 128 * i;
            for (int e = 0; e < NE; ++e)
                acc[e] += xv[i].x * gateT[e * INL + c] + xv[i].y * gateT[e * INL + c + 1];
        }
        for (int e = 0; e < NE; ++e) {
            float a = acc[e];
            for (int off = 32; off >= 1; off >>= 1) a += __shfl_xor(a, off, 64);
            acc[e] = a;
        }
        float logit[NE];
        for (int e = 0; e < NE; ++e) logit[e] = acc[e] + wsRgam[e];

        int i0 = 0; float m0 = logit[0];
        for (int e = 1; e < NE; ++e) if (logit[e] > m0) { m0 = logit[e]; i0 = e; }
        int i1 = -1; float m1 = -3.4e38f;
        for (int e = 0; e < NE; ++e) if (e != i0 && logit[e] > m1) { m1 = logit[e]; i1 = e; }

        float S = 0.f;
        for (int e = 0; e < NE; ++e) S += expf(logit[e] - m0);
        float rw0 = 1.0f / S;
        float rw1 = expf(m1 - m0) / S;

        if (lane == 0) {
            selE[t] = i0 | (i1 << 8);
            selW[t] = make_float4(rw0 * wsGam[i0], rw1 * wsGam[i1], rw0, rw1);
        }
    }
}

// ================= K3: Wt transpose, vectorized =================
// [e][l][d] fp32 -> [e][d][l] bf16.  Reads: float4/lane.  Writes: 16 B/lane
// (8 bf16 along l) -> 8x fewer write instructions than 2 B/lane.
// LDS tile pad 65: all read/write phases <=2-way bank aliasing (free).
__global__ __launch_bounds__(256)
void k_wt(const float* __restrict__ expert_w, ushort_t* __restrict__ wt) {
    __shared__ float tile[64][65];
    int bx = blockIdx.x;
    int e = bx >> 6, rem = bx & 63;
    int lt = (rem >> 3) * 64, dt = (rem & 7) * 64;
    int tid = threadIdx.x;

    int lr = tid >> 4, dc = (tid & 15) * 4;
    for (int p = 0; p < 4; ++p) {
        int l = p * 16 + lr;
        float4 v = *(const float4*)(expert_w + (size_t)(e * INL + lt + l) * OUTL + dt + dc);
        tile[l][dc] = v.x; tile[l][dc + 1] = v.y;
        tile[l][dc + 2] = v.z; tile[l][dc + 3] = v.w;
    }
    __syncthreads();

    for (int i = 0; i < 2; ++i) {
        int ch = tid + i * 256;            // 512 chunks: d = ch>>3, lc = ch&7
        int d = ch >> 3, lc = ch & 7;
        uint4 o;
        o.x = pkbf(tile[lc * 8 + 0][d], tile[lc * 8 + 1][d]);
        o.y = pkbf(tile[lc * 8 + 2][d], tile[lc * 8 + 3][d]);
        o.z = pkbf(tile[lc * 8 + 4][d], tile[lc * 8 + 5][d]);
        o.w = pkbf(tile[lc * 8 + 6][d], tile[lc * 8 + 7][d]);
        *(uint4*)(wt + (size_t)(e * OUTL + dt + d) * INL + lt + lc * 8) = o;
    }
}

// ================= K4: dense all-expert GEMM (fold variant) =================
// r11 structure bit-for-bit (M64xN64, 4 blocks/CU, DMA dbuf, 0-conflict
// swizzle) EXCEPT: A packed UNSCALED once per kc (shared across 8 experts);
// per expert MFMA into acc (C=0 start), then fold comb += wv4[row][e]*acc.
// Cuts per-step pack VALU 24 -> ~18 and decouples pack from the e-loop.
__global__ __launch_bounds__(256, 4)
void k_gemm(const float* __restrict__ x, const ushort_t* __restrict__ wt,
            const int* __restrict__ selE, const float4* __restrict__ selW,
            const float* __restrict__ wsBet, float* __restrict__ out) {
    int bx = blockIdx.x;
    int rt = bx & 127;                 // token slab: rows rt*64..+64
    int ct = bx >> 7;                  // col slab: ct*64..+64
    __shared__ ushort_t Blds[2][64 * 64];   // 2 x 8 KB, swizzled [col][slot]

    int tid = threadIdx.x;
    int wid = tid >> 6, lane = tid & 63;
    int wm = wid * 16;                 // wave's 16-row slice
    int mrow = lane & 15, laneq = lane >> 4, q8 = laneq * 8, qr = laneq * 4;

    // fold weights for this lane's 4 C-rows (wm+qr+ri) x 8 experts
    float wv4[4][NE];
    for (int ri = 0; ri < 4; ++ri) {
        int tok = rt * 64 + wm + qr + ri;
        int es = selE[tok];
        float4 w4 = selW[tok];
        int e0 = es & 255, e1 = es >> 8;
        for (int e = 0; e < NE; ++e)
            wv4[ri][e] = (e == e0) ? w4.x : ((e == e1) ? w4.y : 0.f);
    }
    const float* arowp = x + (size_t)(rt * 64 + wm + mrow) * INL + q8;

    // B staging maps (rotate swizzle, proven 0-conflict)
    int c0 = tid, c1 = tid + 256;
    int col0 = c0 >> 3, kg0 = ((c0 & 7) - col0) & 7;
    int col1 = c1 >> 3, kg1 = ((c1 & 7) - col1) & 7;
    const ushort_t* pB0 = wt + (size_t)(ct * 64 + col0) * INL + kg0 * 8;
    const ushort_t* pB1 = wt + (size_t)(ct * 64 + col1) * INL + kg1 * 8;
    ushort_t* ldsW0 = &Blds[0][0] + (wid * 64) * 8;        // + buf*4096
    ushort_t* ldsW1 = &Blds[0][0] + (256 + wid * 64) * 8;

    int fcol[4], frot0[4];
    for (int nt = 0; nt < 4; ++nt) {
        fcol[nt] = nt * 16 + mrow;
        frot0[nt] = (laneq + fcol[nt]) & 7;
    }

    floatx4 comb[4];
    for (int nt = 0; nt < 4; ++nt) comb[nt] = (floatx4){0.f, 0.f, 0.f, 0.f};
    const floatx4 zf = (floatx4){0.f, 0.f, 0.f, 0.f};

    // prologue: DMA tile (kc=0,e=0) into buf0, drain
    dma16(pB0, ldsW0);
    dma16(pB1, ldsW1);
    __syncthreads();

    #pragma unroll 1
    for (int kc = 0; kc < 8; ++kc) {
        // load + pack UNSCALED A fragments once per kc (reused by all 8 experts)
        union { uint4 u; short8 s; } af[2];
        for (int ks = 0; ks < 2; ++ks) {
            const float* p = arowp + kc * 64 + ks * 32;
            float4 a0 = *(const float4*)p;
            float4 a1 = *(const float4*)(p + 4);
            af[ks].u.x = pkbf(a0.x, a0.y);
            af[ks].u.y = pkbf(a0.z, a0.w);
            af[ks].u.z = pkbf(a1.x, a1.y);
            af[ks].u.w = pkbf(a1.z, a1.w);
        }

        #pragma unroll
        for (int e = 0; e < NE; ++e) {
            int step = kc * 8 + e;
            int buf = step & 1;
            // issue DMA for next step into the other buffer (flies under compute)
            int ne = e + 1, nkc = kc;
            if (ne == NE) { ne = 0; nkc = kc + 1; }
            if (nkc < 8) {
                size_t off = (size_t)ne * EOFF + (size_t)nkc * 64;
                int nb = (step + 1) & 1;
                dma16(pB0 + off, ldsW0 + nb * 4096);
                dma16(pB1 + off, ldsW1 + nb * 4096);
            }

            // per-expert MFMA into acc (from zero), then fold into comb
            const ushort_t* B = &Blds[buf][0];
            floatx4 acc[4];
            for (int nt = 0; nt < 4; ++nt) {
                int cb = fcol[nt] * 64;
                short8 b0 = *(const short8*)&B[cb + frot0[nt] * 8];
                short8 b1 = *(const short8*)&B[cb + ((frot0[nt] + 4) & 7) * 8];
                acc[nt] = __builtin_amdgcn_mfma_f32_16x16x32_bf16(af[0].s, b0, zf, 0, 0, 0);
                acc[nt] = __builtin_amdgcn_mfma_f32_16x16x32_bf16(af[1].s, b1, acc[nt], 0, 0, 0);
            }
            for (int nt = 0; nt < 4; ++nt)
                for (int ri = 0; ri < 4; ++ri)
                    comb[nt][ri] += wv4[ri][e] * acc[nt][ri];
            __syncthreads();   // drain next-DMA (overlapped) + release buf readers
        }
    }

    // epilogue: out = comb + rw0*bet_eff[e0] + rw1*bet_eff[e1], single store
    for (int ri = 0; ri < 4; ++ri) {
        int row = wm + qr + ri;
        int tok = rt * 64 + row;
        int es = selE[tok];
        float4 w4 = selW[tok];
        int e0 = es & 255, e1 = es >> 8;
        for (int nt = 0; nt < 4; ++nt) {
            int col = ct * 64 + nt * 16 + mrow;
            float bet = w4.z * wsBet[e0 * OUTL + col] + w4.w * wsBet[e1 * OUTL + col];
            out[(size_t)tok * OUTL + col] = comb[nt][ri] + bet;
        }
    }
}

extern "C" void kernel_launch(void* const* d_in, const int* in_sizes, int n_in,
                              void* d_out, int out_size, void* d_ws, size_t ws_size,
                              hipStream_t stream) {
    const float* x        = (const float*)d_in[0];
    const float* ins      = (const float*)d_in[1];
    const float* gate_w   = (const float*)d_in[2];
    const float* expert_w = (const float*)d_in[3];
    const float* expert_b = (const float*)d_in[4];
    const float* gamma_w  = (const float*)d_in[5];
    const float* beta_w   = (const float*)d_in[6];
    const float* rmod_w   = (const float*)d_in[7];
    float* out = (float*)d_out;

    char* ws = (char*)d_ws;
    float*    wsGam  = (float*)(ws + WS_GAM);
    float*    wsRgam = (float*)(ws + WS_RGAM);
    float*    wsBet  = (float*)(ws + WS_BET);
    int*      selE   = (int*)(ws + WS_SELE);
    float4*   selW   = (float4*)(ws + WS_SELW);
    ushort_t* wt     = (ushort_t*)(ws + WS_WT);

    k_betstats<<<129, 256, 0, stream>>>(ins, gamma_w, rmod_w, beta_w, expert_b,
                                        wsBet, wsGam, wsRgam);
    k_route<<<N_TOK / 16, 256, 0, stream>>>(x, gate_w, wsGam, wsRgam, selE, selW);
    k_wt<<<512, 256, 0, stream>>>(expert_w, wt);
    k_gemm<<<1024, 256, 0, stream>>>(x, wt, selE, selW, wsBet, out);
}

// Round 13
// 156.302 us; speedup vs baseline: 1.7301x; 1.7301x over previous
//
#include <hip/hip_runtime.h>
#include <hip/hip_bf16.h>

// Problem constants
#define N_TOK 8192
#define INL   512
#define OUTL  512
#define NE    8
#define NI    16
#define EOFF  (OUTL * INL)   // elems per expert in wt

typedef unsigned short ushort_t;
typedef unsigned int   uint_t;
typedef short  short8  __attribute__((ext_vector_type(8)));
typedef float  floatx4 __attribute__((ext_vector_type(4)));

// ---------------- workspace layout (bytes) ----------------
#define WS_GAM    2048u      // float[8]   : gam[e]
#define WS_RGAM   2080u      // float[8]   : router_gamma[e]
#define WS_BET    2112u      // float[4096]: bet_eff[e][d] = bet + gam*b
#define WS_SELE   18496u     // int[8192]  : e0 | e1<<8
#define WS_SELW   51264u     // float4[8192]: {rw0*gam0, rw1*gam1, rw0, rw1}
#define WS_WT     182336u    // ushort[8*512*512] : W^T bf16 [e][d][l]

__device__ __forceinline__ uint_t pkbf(float a, float b) {
    __hip_bfloat162 h = __float22bfloat162_rn(make_float2(a, b));  // v_cvt_pk_bf16_f32
    union { __hip_bfloat162 h2; uint_t u; } cv;
    cv.h2 = h;
    return cv.u;
}
// async global->LDS DMA, 16 B per lane; LDS dest = wave-uniform base + lane*16
__device__ __forceinline__ void dma16(const ushort_t* g, ushort_t* l) {
    __builtin_amdgcn_global_load_lds(
        (const __attribute__((address_space(1))) void*)g,
        (__attribute__((address_space(3))) void*)l,
        16, 0, 0);
}

// ================= K1: bet_eff + stats (parallel, coalesced) =================
// 512 threads/block. blocks [0,128): bet_eff for (e = bx>>4, 32 d's).
//   lane reads float4 ALONG d (8 lanes = 128 B contiguous per h-row);
//   64 h-streams in flight, only 8 serial iters/thread; LDS tree-reduce.
// block 128: stats -> wsGam, wsRgam.
__global__ __launch_bounds__(512)
void k_betstats(const float* __restrict__ ins,
                const float* __restrict__ gamma_w,
                const float* __restrict__ rmod_w,
                const float* __restrict__ beta_w,
                const float* __restrict__ expert_b,
                float* __restrict__ wsBet,
                float* __restrict__ wsGam, float* __restrict__ wsRgam) {
    __shared__ float sS[INL];          // 2 KB
    __shared__ float red[64 * 32];     // 8 KB  [hg][d]
    __shared__ float aux[1];
    int bx = blockIdx.x, tid = threadIdx.x;

    // s[h] = sum_n ins[n,h]  (one h per thread, coalesced per n)
    if (tid < INL) {
        float a = 0.f;
        for (int n = 0; n < NI; ++n) a += ins[n * INL + tid];
        sS[tid] = a;
    }
    __syncthreads();

    if (bx < 128) {
        int e = bx >> 4, dBase = (bx & 15) * 32;
        // gam_e = dot(s, gamma_w[e]) / NI (first wave)
        if (tid < 64) {
            float g = 0.f;
            for (int j = 0; j < 8; ++j) g += sS[tid * 8 + j] * gamma_w[e * INL + tid * 8 + j];
            for (int off = 32; off >= 1; off >>= 1) g += __shfl_xor(g, off, 64);
            if (tid == 0) aux[0] = g * (1.f / NI);
        }
        // partial sums: ld = d-quad, hg = h-stream
        int ld = tid & 7, hg = tid >> 3;            // hg 0..63
        float4 acc = make_float4(0.f, 0.f, 0.f, 0.f);
        for (int j = 0; j < 8; ++j) {
            int h = hg + 64 * j;
            float sv = sS[h];
            float4 v = *(const float4*)(beta_w + (size_t)(e * INL + h) * OUTL + dBase + ld * 4);
            acc.x += sv * v.x; acc.y += sv * v.y;
            acc.z += sv * v.z; acc.w += sv * v.w;
        }
        red[hg * 32 + ld * 4 + 0] = acc.x;
        red[hg * 32 + ld * 4 + 1] = acc.y;
        red[hg * 32 + ld * 4 + 2] = acc.z;
        red[hg * 32 + ld * 4 + 3] = acc.w;
        __syncthreads();
        // reduce 64 hg -> 1 per d (32 d's, one wave; 64 LDS reads each)
        if (tid < 32) {
            float t = 0.f;
            for (int g2 = 0; g2 < 64; ++g2) t += red[g2 * 32 + tid];
            int d = dBase + tid;
            wsBet[e * OUTL + d] = t * (1.f / NI) + aux[0] * expert_b[e * OUTL + d];
        }
        return;
    }

    // stats block
    if (tid < 64) {
        int e = tid & 7, qq = tid >> 3;
        float g = 0.f, r = 0.f;
        for (int j = 0; j < 64; ++j) {
            int h = qq * 64 + j;
            float sv = sS[h];
            g += sv * gamma_w[e * INL + h];
            r += sv * rmod_w[h * NE + e];
        }
        red[tid] = g; red[64 + tid] = r;
    }
    __syncthreads();
    if (tid < NE) {
        float g = 0.f, r = 0.f;
        for (int qq = 0; qq < 8; ++qq) { g += red[qq * 8 + tid]; r += red[64 + qq * 8 + tid]; }
        wsGam[tid]  = g * (1.f / NI);
        wsRgam[tid] = r * (1.f / NI);
    }
}

// ================= K2: router (fp32 logits), 16 tokens/block =================
__global__ void k_route(const float* __restrict__ x,
                        const float* __restrict__ gate_w,
                        const float* __restrict__ wsGam,
                        const float* __restrict__ wsRgam,
                        int* __restrict__ selE, float4* __restrict__ selW) {
    __shared__ float gateT[NE * INL];   // 16 KB, [e][l]
    int tid = threadIdx.x;
    for (int i = 0; i < 16; ++i) {
        int f = tid + 256 * i;
        float v = gate_w[f];
        gateT[(f & 7) * INL + (f >> 3)] = v;
    }
    __syncthreads();

    int w = tid >> 6, lane = tid & 63;
    int tbase = blockIdx.x * 16 + w * 4;

    for (int tt = 0; tt < 4; ++tt) {
        int t = tbase + tt;
        float2 xv[4];
        for (int i = 0; i < 4; ++i)
            xv[i] = *(const float2*)(x + (size_t)t * INL + 2 * lane + 128 * i);

        float acc[NE];
        for (int e = 0; e < NE; ++e) acc[e] = 0.f;
        for (int i = 0; i < 4; ++i) {
            int c = 2 * lane + 128 * i;
            for (int e = 0; e < NE; ++e)
                acc[e] += xv[i].x * gateT[e * INL + c] + xv[i].y * gateT[e * INL + c + 1];
        }
        for (int e = 0; e < NE; ++e) {
            float a = acc[e];
            for (int off = 32; off >= 1; off >>= 1) a += __shfl_xor(a, off, 64);
            acc[e] = a;
        }
        float logit[NE];
        for (int e = 0; e < NE; ++e) logit[e] = acc[e] + wsRgam[e];

        int i0 = 0; float m0 = logit[0];
        for (int e = 1; e < NE; ++e) if (logit[e] > m0) { m0 = logit[e]; i0 = e; }
        int i1 = -1; float m1 = -3.4e38f;
        for (int e = 0; e < NE; ++e) if (e != i0 && logit[e] > m1) { m1 = logit[e]; i1 = e; }

        float S = 0.f;
        for (int e = 0; e < NE; ++e) S += expf(logit[e] - m0);
        float rw0 = 1.0f / S;
        float rw1 = expf(m1 - m0) / S;

        if (lane == 0) {
            selE[t] = i0 | (i1 << 8);
            selW[t] = make_float4(rw0 * wsGam[i0], rw1 * wsGam[i1], rw0, rw1);
        }
    }
}

// ================= K3: Wt transpose, vectorized =================
__global__ __launch_bounds__(256)
void k_wt(const float* __restrict__ expert_w, ushort_t* __restrict__ wt) {
    __shared__ float tile[64][65];
    int bx = blockIdx.x;
    int e = bx >> 6, rem = bx & 63;
    int lt = (rem >> 3) * 64, dt = (rem & 7) * 64;
    int tid = threadIdx.x;

    int lr = tid >> 4, dc = (tid & 15) * 4;
    for (int p = 0; p < 4; ++p) {
        int l = p * 16 + lr;
        float4 v = *(const float4*)(expert_w + (size_t)(e * INL + lt + l) * OUTL + dt + dc);
        tile[l][dc] = v.x; tile[l][dc + 1] = v.y;
        tile[l][dc + 2] = v.z; tile[l][dc + 3] = v.w;
    }
    __syncthreads();

    for (int i = 0; i < 2; ++i) {
        int ch = tid + i * 256;            // 512 chunks: d = ch>>3, lc = ch&7
        int d = ch >> 3, lc = ch & 7;
        uint4 o;
        o.x = pkbf(tile[lc * 8 + 0][d], tile[lc * 8 + 1][d]);
        o.y = pkbf(tile[lc * 8 + 2][d], tile[lc * 8 + 3][d]);
        o.z = pkbf(tile[lc * 8 + 4][d], tile[lc * 8 + 5][d]);
        o.w = pkbf(tile[lc * 8 + 6][d], tile[lc * 8 + 7][d]);
        *(uint4*)(wt + (size_t)(e * OUTL + dt + d) * INL + lt + lc * 8) = o;
    }
}

// ================= K4: dense all-expert GEMM (r11, proven 62 us) =================
__global__ __launch_bounds__(256, 4)
void k_gemm(const float* __restrict__ x, const ushort_t* __restrict__ wt,
            const int* __restrict__ selE, const float4* __restrict__ selW,
            const float* __restrict__ wsBet, float* __restrict__ out) {
    int bx = blockIdx.x;
    int rt = bx & 127;                 // token slab: rows rt*64..+64
    int ct = bx >> 7;                  // col slab: ct*64..+64
    __shared__ ushort_t Blds[2][64 * 64];   // 2 x 8 KB, swizzled [col][slot]

    int tid = threadIdx.x;
    int wid = tid >> 6, lane = tid & 63;
    int wm = wid * 16;                 // wave's 16-row slice
    int mrow = lane & 15, laneq = lane >> 4, q8 = laneq * 8, qr = laneq * 4;

    // combine weights for this lane's A row
    int tokL = rt * 64 + wm + mrow;
    float wv[NE];
    {
        int es = selE[tokL];
        float4 w4 = selW[tokL];
        int e0 = es & 255, e1 = es >> 8;
        for (int e = 0; e < NE; ++e)
            wv[e] = (e == e0) ? w4.x : ((e == e1) ? w4.y : 0.f);
    }
    const float* arowp = x + (size_t)tokL * INL + q8;

    // B staging maps (rotate swizzle, proven 0-conflict)
    int c0 = tid, c1 = tid + 256;
    int col0 = c0 >> 3, kg0 = ((c0 & 7) - col0) & 7;
    int col1 = c1 >> 3, kg1 = ((c1 & 7) - col1) & 7;
    const ushort_t* pB0 = wt + (size_t)(ct * 64 + col0) * INL + kg0 * 8;
    const ushort_t* pB1 = wt + (size_t)(ct * 64 + col1) * INL + kg1 * 8;
    ushort_t* ldsW0 = &Blds[0][0] + (wid * 64) * 8;        // + buf*4096
    ushort_t* ldsW1 = &Blds[0][0] + (256 + wid * 64) * 8;

    // fragment read swizzle
    int fcol[4], frot0[4];
    for (int nt = 0; nt < 4; ++nt) {
        fcol[nt] = nt * 16 + mrow;
        frot0[nt] = (laneq + fcol[nt]) & 7;
    }

    floatx4 comb[4];
    for (int nt = 0; nt < 4; ++nt) comb[nt] = (floatx4){0.f, 0.f, 0.f, 0.f};

    // prologue: DMA tile (kc=0,e=0) into buf0, drain
    dma16(pB0, ldsW0);
    dma16(pB1, ldsW1);
    __syncthreads();

    float4 ar[2][2];   // [ks][half] fp32 A fragments for current kc

    #pragma unroll 1
    for (int kc = 0; kc < 8; ++kc) {
        for (int ks = 0; ks < 2; ++ks) {
            const float* p = arowp + kc * 64 + ks * 32;
            ar[ks][0] = *(const float4*)p;
            ar[ks][1] = *(const float4*)(p + 4);
        }

        #pragma unroll
        for (int e = 0; e < NE; ++e) {
            int step = kc * 8 + e;
            int buf = step & 1;
            // issue DMA for next step into the other buffer (flies under compute)
            int ne = e + 1, nkc = kc;
            if (ne == NE) { ne = 0; nkc = kc + 1; }
            if (nkc < 8) {
                size_t off = (size_t)ne * EOFF + (size_t)nkc * 64;
                int nb = (step + 1) & 1;
                dma16(pB0 + off, ldsW0 + nb * 4096);
                dma16(pB1 + off, ldsW1 + nb * 4096);
            }

            // compute current step from buf
            const ushort_t* B = &Blds[buf][0];
            short8 bf[4][2];
            for (int nt = 0; nt < 4; ++nt) {
                int cb = fcol[nt] * 64;
                bf[nt][0] = *(const short8*)&B[cb + frot0[nt] * 8];
                bf[nt][1] = *(const short8*)&B[cb + ((frot0[nt] + 4) & 7) * 8];
            }
            float w = wv[e];
            for (int ks = 0; ks < 2; ++ks) {
                union { uint4 u; short8 s; } af;
                float4 a0 = ar[ks][0], a1 = ar[ks][1];
                af.u.x = pkbf(a0.x * w, a0.y * w);
                af.u.y = pkbf(a0.z * w, a0.w * w);
                af.u.z = pkbf(a1.x * w, a1.y * w);
                af.u.w = pkbf(a1.z * w, a1.w * w);
                for (int nt = 0; nt < 4; ++nt)
                    comb[nt] = __builtin_amdgcn_mfma_f32_16x16x32_bf16(
                        af.s, bf[nt][ks], comb[nt], 0, 0, 0);
            }
            __syncthreads();   // drain next-DMA (overlapped) + release buf readers
        }
    }

    // epilogue: out = comb + rw0*bet_eff[e0] + rw1*bet_eff[e1], single store
    for (int ri = 0; ri < 4; ++ri) {
        int row = wm + qr + ri;
        int tok = rt * 64 + row;
        int es = selE[tok];
        float4 w4 = selW[tok];
        int e0 = es & 255, e1 = es >> 8;
        for (int nt = 0; nt < 4; ++nt) {
            int col = ct * 64 + nt * 16 + mrow;
            float bet = w4.z * wsBet[e0 * OUTL + col] + w4.w * wsBet[e1 * OUTL + col];
            out[(size_t)tok * OUTL + col] = comb[nt][ri] + bet;
        }
    }
}

extern "C" void kernel_launch(void* const* d_in, const int* in_sizes, int n_in,
                              void* d_out, int out_size, void* d_ws, size_t ws_size,
                              hipStream_t stream) {
    const float* x        = (const float*)d_in[0];
    const float* ins      = (const float*)d_in[1];
    const float* gate_w   = (const float*)d_in[2];
    const float* expert_w = (const float*)d_in[3];
    const float* expert_b = (const float*)d_in[4];
    const float* gamma_w  = (const float*)d_in[5];
    const float* beta_w   = (const float*)d_in[6];
    const float* rmod_w   = (const float*)d_in[7];
    float* out = (float*)d_out;

    char* ws = (char*)d_ws;
    float*    wsGam  = (float*)(ws + WS_GAM);
    float*    wsRgam = (float*)(ws + WS_RGAM);
    float*    wsBet  = (float*)(ws + WS_BET);
    int*      selE   = (int*)(ws + WS_SELE);
    float4*   selW   = (float4*)(ws + WS_SELW);
    ushort_t* wt     = (ushort_t*)(ws + WS_WT);

    k_betstats<<<129, 512, 0, stream>>>(ins, gamma_w, rmod_w, beta_w, expert_b,
                                        wsBet, wsGam, wsRgam);
    k_route<<<N_TOK / 16, 256, 0, stream>>>(x, gate_w, wsGam, wsRgam, selE, selW);
    k_wt<<<512, 256, 0, stream>>>(expert_w, wt);
    k_gemm<<<1024, 256, 0, stream>>>(x, wt, selE, selW, wsBet, out);
}